// Round 4
// baseline (843.540 us; speedup 1.0000x reference)
//
#include <hip/hip_runtime.h>

// LSTM: B=4096, T=512, I=2, H=50, O=3.
// Round 4: lane = hidden unit (pad 50->64), wave = 4 batch rows, block =
// 2 waves = 8 rows, 512 blocks (2 blocks/CU, 1 wave/SIMD; LDS caps occupancy
// so VGPR budget is wide open). Weights live in LDS as [k][u] float4
// (Wi,Wf,Wg,Wo) read once per wave per t (ds_read_b128, conflict-free) and
// amortized over 4 rows. All packed FMAs are inline-asm v_pk_fma_f32 with
// op_sel broadcast of the h word -> zero splat movs. No barriers in the
// T loop (h rows are wave-private).

typedef float v2f __attribute__((ext_vector_type(2)));

#define T_STEPS 512
#define HID     50
#define NB      4            // batch rows per wave
#define WPB     2            // waves per block
#define RPB     (NB * WPB)   // 8 rows per block

struct __align__(16) W2 { v2f ifp, gop; };   // (Wi,Wf),(Wg,Wo) for one (k,u)
struct __align__(16) H2 { v2f a, b; };       // (h[k],h[k+1]),(h[k+2],h[k+3])

__device__ __forceinline__ float fsig(float x) {
    float e = __builtin_amdgcn_exp2f(-1.442695040888963f * x);
    return __builtin_amdgcn_rcpf(1.0f + e);
}
__device__ __forceinline__ float ftanh(float x) {
    float e = __builtin_amdgcn_exp2f(2.885390081777927f * x);
    return 1.0f - 2.0f * __builtin_amdgcn_rcpf(e + 1.0f);
}

// acc += w * broadcast(h.lo)   (both result halves use h's low word)
__device__ __forceinline__ void pk_fma_lo(v2f& acc, v2f w, v2f h) {
    asm("v_pk_fma_f32 %0, %1, %2, %0 op_sel:[0,0,0] op_sel_hi:[1,0,1]"
        : "+v"(acc) : "v"(w), "v"(h));
}
// acc += w * broadcast(h.hi)
__device__ __forceinline__ void pk_fma_hi(v2f& acc, v2f w, v2f h) {
    asm("v_pk_fma_f32 %0, %1, %2, %0 op_sel:[0,1,0] op_sel_hi:[1,1,1]"
        : "+v"(acc) : "v"(w), "v"(h));
}

__global__ __launch_bounds__(128, 1) void lstm_fused_kernel(
    const float* __restrict__ x,     // [B,T,2]
    const float* __restrict__ W_ih,  // [200,2]
    const float* __restrict__ W_hh,  // [200,50]
    const float* __restrict__ b_ih,  // [200]
    const float* __restrict__ b_hh,  // [200]
    const float* __restrict__ W_fc,  // [3,50]
    const float* __restrict__ b_fc,  // [3]
    float* __restrict__ out)         // [B,3]
{
    __shared__ W2 wlds[HID * 64];                    // 51.2 KB
    __shared__ __align__(16) float h_lds[RPB * 64];  // 2 KB

    const int tid = threadIdx.x;
    const int hk  = tid & 63;
    const int wv  = tid >> 6;

    // ---- one-time staging of W_hh, transposed + gate-interleaved ----
    for (int idx = tid; idx < HID * 64; idx += 128) {
        int k = idx >> 6, u = idx & 63;
        W2 w;
        if (u < HID) {
            w.ifp = (v2f){W_hh[(0 * HID + u) * HID + k], W_hh[(1 * HID + u) * HID + k]};
            w.gop = (v2f){W_hh[(2 * HID + u) * HID + k], W_hh[(3 * HID + u) * HID + k]};
        } else {
            w.ifp = (v2f){0.f, 0.f};
            w.gop = (v2f){0.f, 0.f};
        }
        wlds[idx] = w;
    }
    for (int idx = tid; idx < RPB * 64; idx += 128) h_lds[idx] = 0.f;

    // ---- per-lane gate constants ----
    const int j = (hk < HID) ? hk : 0;
    const int ji = 0 * HID + j, jf = 1 * HID + j, jg = 2 * HID + j, jo = 3 * HID + j;
    v2f bif   = (v2f){b_ih[ji] + b_hh[ji], b_ih[jf] + b_hh[jf]};
    v2f bgo   = (v2f){b_ih[jg] + b_hh[jg], b_ih[jo] + b_hh[jo]};
    v2f xw0if = (v2f){W_ih[ji * 2 + 0], W_ih[jf * 2 + 0]};
    v2f xw1if = (v2f){W_ih[ji * 2 + 1], W_ih[jf * 2 + 1]};
    v2f xw0go = (v2f){W_ih[jg * 2 + 0], W_ih[jo * 2 + 0]};
    v2f xw1go = (v2f){W_ih[jg * 2 + 1], W_ih[jo * 2 + 1]};

    const int b0 = blockIdx.x * RPB + wv * NB;
    const float* xbase = x + (size_t)b0 * (T_STEPS * 2);

    float c[NB];
    v2f   xc[NB];
#pragma unroll
    for (int r = 0; r < NB; ++r) {
        c[r]  = 0.f;
        xc[r] = *(const v2f*)(xbase + r * (T_STEPS * 2));
    }

    __syncthreads();   // weights + h zeros visible

    const int hrow = wv * NB * 64;

    for (int t = 0; t < T_STEPS; ++t) {
        // prefetch next timestep's x early (covers HBM latency under the k-loop)
        const int tn = (t + 1 < T_STEPS) ? t + 1 : t;
        v2f xn[NB];
#pragma unroll
        for (int r = 0; r < NB; ++r)
            xn[r] = *(const v2f*)(xbase + r * (T_STEPS * 2) + tn * 2);

        // init accumulators with bias + x contribution (packed, op_sel)
        v2f aif[NB], ago[NB];
#pragma unroll
        for (int r = 0; r < NB; ++r) {
            aif[r] = bif;
            pk_fma_lo(aif[r], xw0if, xc[r]);
            pk_fma_hi(aif[r], xw1if, xc[r]);
            ago[r] = bgo;
            pk_fma_lo(ago[r], xw0go, xc[r]);
            pk_fma_hi(ago[r], xw1go, xc[r]);
        }

        // recurrent matvec: weights streamed from LDS, h broadcast-read
#pragma unroll
        for (int kk = 0; kk < 48; kk += 4) {
            H2 hp[NB];
#pragma unroll
            for (int r = 0; r < NB; ++r)
                hp[r] = *(const H2*)&h_lds[hrow + r * 64 + kk];
#pragma unroll
            for (int q = 0; q < 4; ++q) {
                W2 w = wlds[(kk + q) * 64 + hk];
#pragma unroll
                for (int r = 0; r < NB; ++r) {
                    if (q == 0) {
                        pk_fma_lo(aif[r], w.ifp, hp[r].a);
                        pk_fma_lo(ago[r], w.gop, hp[r].a);
                    } else if (q == 1) {
                        pk_fma_hi(aif[r], w.ifp, hp[r].a);
                        pk_fma_hi(ago[r], w.gop, hp[r].a);
                    } else if (q == 2) {
                        pk_fma_lo(aif[r], w.ifp, hp[r].b);
                        pk_fma_lo(ago[r], w.gop, hp[r].b);
                    } else {
                        pk_fma_hi(aif[r], w.ifp, hp[r].b);
                        pk_fma_hi(ago[r], w.gop, hp[r].b);
                    }
                }
            }
        }
        {   // tail k = 48, 49
            v2f hT[NB];
#pragma unroll
            for (int r = 0; r < NB; ++r)
                hT[r] = *(const v2f*)&h_lds[hrow + r * 64 + 48];
#pragma unroll
            for (int q = 0; q < 2; ++q) {
                W2 w = wlds[(48 + q) * 64 + hk];
#pragma unroll
                for (int r = 0; r < NB; ++r) {
                    if (q == 0) {
                        pk_fma_lo(aif[r], w.ifp, hT[r]);
                        pk_fma_lo(ago[r], w.gop, hT[r]);
                    } else {
                        pk_fma_hi(aif[r], w.ifp, hT[r]);
                        pk_fma_hi(ago[r], w.gop, hT[r]);
                    }
                }
            }
        }

        // gates + state update + h publish (wave-private rows, no barrier)
#pragma unroll
        for (int r = 0; r < NB; ++r) {
            float ig = fsig(aif[r].x), fg = fsig(aif[r].y);
            float gg = ftanh(ago[r].x), og = fsig(ago[r].y);
            c[r] = fg * c[r] + ig * gg;
            h_lds[hrow + r * 64 + hk] = og * ftanh(c[r]);
            xc[r] = xn[r];
        }
    }

    // ---- final FC: out[b][o] = h . W_fc[o] + b_fc[o] ----
    if (hk < 3 * NB) {
        int r = hk / 3, o = hk - r * 3;
        float s = b_fc[o];
        const float* hp = &h_lds[hrow + r * 64];
        for (int k = 0; k < HID; ++k)
            s += hp[k] * W_fc[o * HID + k];
        out[(size_t)(b0 + r) * 3 + o] = s;
    }
}

extern "C" void kernel_launch(void* const* d_in, const int* in_sizes, int n_in,
                              void* d_out, int out_size, void* d_ws, size_t ws_size,
                              hipStream_t stream) {
    const float* x    = (const float*)d_in[0];
    const float* W_ih = (const float*)d_in[1];
    const float* W_hh = (const float*)d_in[2];
    const float* b_ih = (const float*)d_in[3];
    const float* b_hh = (const float*)d_in[4];
    const float* W_fc = (const float*)d_in[5];
    const float* b_fc = (const float*)d_in[6];
    float* out = (float*)d_out;

    dim3 grid(4096 / RPB);   // 512 blocks
    dim3 block(128);         // 2 waves
    lstm_fused_kernel<<<grid, block, 0, stream>>>(x, W_ih, W_hh, b_ih, b_hh,
                                                  W_fc, b_fc, out);
}

// Round 5
// 634.504 us; speedup vs baseline: 1.3294x; 1.3294x over previous
//
#include <hip/hip_runtime.h>

// LSTM B=4096, T=512, I=2, H=50, O=3 — MFMA bf16x3 emulation.
// Block = 8 batch rows (M=8 in a 16x16x32 tile, rows 8..15 pad), 4 waves;
// wave w owns u-block u=[16w,16w+16) and its 4 gate tiles (i,f,g,o) so all
// gates of unit u sit in the same lane (C: col=lane&15, row=(lane>>4)*4+reg).
// W_hh^T frags (bf16 hi+lo) are VGPR-resident; h (bf16 hi+lo) double-buffers
// through LDS with ONE barrier per timestep. acc = Ahi*Bhi + Alo*Bhi + Ahi*Blo.
// 512 blocks x 256 thr -> 2 blocks/CU, 2 waves/SIMD.

typedef short bf16x8 __attribute__((ext_vector_type(8)));
typedef float f32x4  __attribute__((ext_vector_type(4)));

#define T_STEPS 512
#define HID     50
#define ROWS    8
#define HSTRIDE 144   // bytes per h row: 16B-aligned, 36 dwords -> 2-way banks max

__device__ __forceinline__ float fsig(float x) {
    float e = __builtin_amdgcn_exp2f(-1.442695040888963f * x);
    return __builtin_amdgcn_rcpf(1.0f + e);
}
__device__ __forceinline__ float ftanh(float x) {
    float e = __builtin_amdgcn_exp2f(2.885390081777927f * x);
    return 1.0f - 2.0f * __builtin_amdgcn_rcpf(e + 1.0f);
}
__device__ __forceinline__ short f32_to_bf16_rn(float f) {
    unsigned u = __float_as_uint(f);
    unsigned r = (u + 0x7fffu + ((u >> 16) & 1u)) >> 16;
    return (short)r;
}
__device__ __forceinline__ float bf16_to_f32(short s) {
    return __uint_as_float(((unsigned)(unsigned short)s) << 16);
}

__global__ __launch_bounds__(256, 2) void lstm_mfma_kernel(
    const float* __restrict__ x,     // [B,T,2]
    const float* __restrict__ W_ih,  // [200,2]
    const float* __restrict__ W_hh,  // [200,50]
    const float* __restrict__ b_ih,  // [200]
    const float* __restrict__ b_hh,  // [200]
    const float* __restrict__ W_fc,  // [3,50]
    const float* __restrict__ b_fc,  // [3]
    float* __restrict__ out)         // [B,3]
{
    __shared__ __align__(16) float x_lds[ROWS * T_STEPS * 2];   // 32 KB
    __shared__ __align__(16) char  hbuf[2][2][16 * HSTRIDE];    // [buf][hi/lo] 9.2 KB

    const int tid  = threadIdx.x;
    const int lane = tid & 63;
    const int wv   = tid >> 6;          // u-block 0..3
    const int ucol = lane & 15;         // B/C col within tile; also A row
    const int grp  = lane >> 4;         // k-group / C row group
    const int u    = wv * 16 + ucol;    // global hidden unit 0..63 (50 real)
    const int b0   = blockIdx.x * ROWS;

    // ---- stage x for this block's 8 rows (contiguous in global) ----
    {
        const float4* src = (const float4*)(x + (size_t)b0 * (T_STEPS * 2));
        float4* dst = (float4*)x_lds;
        for (int i = tid; i < ROWS * T_STEPS * 2 / 4; i += 256)
            dst[i] = src[i];
    }
    // ---- zero h double-buffers (h0 = 0) ----
    {
        int* hz = (int*)hbuf;
        for (int i = tid; i < (int)(sizeof(hbuf) / 4); i += 256)
            hz[i] = 0;
    }

    // ---- build W_hh^T B-frags (bf16 hi/lo) in VGPRs: [gate][ktile] ----
    // B[k][n]: lane holds col n=ucol (-> gate-row j=g*50+u), k = kt*32+grp*8+e
    bf16x8 whi[4][2], wlo[4][2];
#pragma unroll
    for (int g = 0; g < 4; ++g) {
#pragma unroll
        for (int kt = 0; kt < 2; ++kt) {
            bf16x8 hi8, lo8;
#pragma unroll
            for (int e = 0; e < 8; ++e) {
                int k = kt * 32 + grp * 8 + e;
                float v = (u < HID && k < HID) ? W_hh[(g * HID + u) * HID + k] : 0.f;
                short h = f32_to_bf16_rn(v);
                short l = f32_to_bf16_rn(v - bf16_to_f32(h));
                hi8[e] = h;
                lo8[e] = l;
            }
            whi[g][kt] = hi8;
            wlo[g][kt] = lo8;
        }
    }

    // ---- per-lane gate constants (bias + x weights for unit u) ----
    float b4[4], wi0[4], wi1[4];
    {
        const int uj = (u < HID) ? u : 0;
#pragma unroll
        for (int g = 0; g < 4; ++g) {
            int j = g * HID + uj;
            b4[g]  = b_ih[j] + b_hh[j];
            wi0[g] = W_ih[2 * j + 0];
            wi1[g] = W_ih[2 * j + 1];
        }
    }

    float c4[4]   = {0.f, 0.f, 0.f, 0.f};
    float hreg[4] = {0.f, 0.f, 0.f, 0.f};

    const int abyte = ucol * HSTRIDE + grp * 16;   // A-frag byte offset

    __syncthreads();

    int pb = 0;
    for (int t = 0; t < T_STEPS; ++t) {
        // x[t] for my 4 C-rows (broadcast LDS reads)
        float2 xm[4];
#pragma unroll
        for (int r = 0; r < 4; ++r) {
            int m = (grp * 4 + r) & 7;     // clamp pad rows into valid memory
            xm[r] = *(const float2*)&x_lds[m * (T_STEPS * 2) + t * 2];
        }

        // A-frags: h hi/lo, 2 k-tiles
        const char* hb = hbuf[pb][0];
        const char* lb = hbuf[pb][1];
        bf16x8 ah0 = *(const bf16x8*)(hb + abyte);
        bf16x8 ah1 = *(const bf16x8*)(hb + abyte + 64);
        bf16x8 al0 = *(const bf16x8*)(lb + abyte);
        bf16x8 al1 = *(const bf16x8*)(lb + abyte + 64);

        // 4 gate tiles x (2 ktiles x 3 emulation terms) = 24 MFMA
        f32x4 acc[4];
#pragma unroll
        for (int g = 0; g < 4; ++g) {
            f32x4 a = {0.f, 0.f, 0.f, 0.f};
            a = __builtin_amdgcn_mfma_f32_16x16x32_bf16(ah0, whi[g][0], a, 0, 0, 0);
            a = __builtin_amdgcn_mfma_f32_16x16x32_bf16(ah1, whi[g][1], a, 0, 0, 0);
            a = __builtin_amdgcn_mfma_f32_16x16x32_bf16(al0, whi[g][0], a, 0, 0, 0);
            a = __builtin_amdgcn_mfma_f32_16x16x32_bf16(al1, whi[g][1], a, 0, 0, 0);
            a = __builtin_amdgcn_mfma_f32_16x16x32_bf16(ah0, wlo[g][0], a, 0, 0, 0);
            a = __builtin_amdgcn_mfma_f32_16x16x32_bf16(ah1, wlo[g][1], a, 0, 0, 0);
            acc[g] = a;
        }

        // gates + state update + bf16 hi/lo publish to other buffer
        char* dhi = hbuf[pb ^ 1][0];
        char* dlo = hbuf[pb ^ 1][1];
#pragma unroll
        for (int r = 0; r < 4; ++r) {
            float pi = acc[0][r] + b4[0] + xm[r].x * wi0[0] + xm[r].y * wi1[0];
            float pf = acc[1][r] + b4[1] + xm[r].x * wi0[1] + xm[r].y * wi1[1];
            float pg = acc[2][r] + b4[2] + xm[r].x * wi0[2] + xm[r].y * wi1[2];
            float po = acc[3][r] + b4[3] + xm[r].x * wi0[3] + xm[r].y * wi1[3];
            float ig = fsig(pi), fg = fsig(pf), og = fsig(po), gg = ftanh(pg);
            float c = fg * c4[r] + ig * gg;
            c4[r] = c;
            float h = og * ftanh(c);
            hreg[r] = h;
            short hh = f32_to_bf16_rn(h);
            short hl = f32_to_bf16_rn(h - bf16_to_f32(hh));
            int m = grp * 4 + r;               // 0..15 (8..15 = pad rows)
            *(short*)(dhi + m * HSTRIDE + u * 2) = hh;
            *(short*)(dlo + m * HSTRIDE + u * 2) = hl;
        }
        pb ^= 1;
        __syncthreads();   // writes visible before next step's A reads
    }

    // ---- final FC from fp32 h (reuse x_lds) ----
    float* hfin = x_lds;   // [16][64]
#pragma unroll
    for (int r = 0; r < 4; ++r) {
        int m = grp * 4 + r;
        hfin[m * 64 + u] = hreg[r];
    }
    __syncthreads();
    if (tid < ROWS * 3) {
        int m = tid / 3, o = tid % 3;
        float s = b_fc[o];
        for (int k = 0; k < HID; ++k)
            s += hfin[m * 64 + k] * W_fc[o * HID + k];
        out[(size_t)(b0 + m) * 3 + o] = s;
    }
}

extern "C" void kernel_launch(void* const* d_in, const int* in_sizes, int n_in,
                              void* d_out, int out_size, void* d_ws, size_t ws_size,
                              hipStream_t stream) {
    const float* x    = (const float*)d_in[0];
    const float* W_ih = (const float*)d_in[1];
    const float* W_hh = (const float*)d_in[2];
    const float* b_ih = (const float*)d_in[3];
    const float* b_hh = (const float*)d_in[4];
    const float* W_fc = (const float*)d_in[5];
    const float* b_fc = (const float*)d_in[6];
    float* out = (float*)d_out;

    dim3 grid(4096 / ROWS);   // 512 blocks
    dim3 block(256);          // 4 waves
    lstm_mfma_kernel<<<grid, block, 0, stream>>>(x, W_ih, W_hh, b_ih, b_hh,
                                                 W_fc, b_fc, out);
}

// Round 6
// 559.826 us; speedup vs baseline: 1.5068x; 1.1334x over previous
//
#include <hip/hip_runtime.h>

// LSTM B=4096, T=512, I=2, H=50, O=3 — MFMA bf16x3, round 6.
// K-dim carries everything: k=0..49 h-units, k=50/51 x0/x1, k=52 const-1.0
// (B columns: W_hh / W_ih / bias), so acc == full gate preactivation.
// h cells packed (hi,lo) b32 in [m][k] stride-272B planes, double-buffered,
// ONE barrier per t. Block = 8 rows, 4 waves (wave w owns units 16w..16w+15,
// all 4 gates). 512 blocks x 256 thr -> 2 blocks/CU, 2 waves/SIMD.

typedef short bf16x8 __attribute__((ext_vector_type(8)));
typedef float f32x4  __attribute__((ext_vector_type(4)));

#define T_STEPS 512
#define HID     50
#define ROWS    8                 // real batch rows per block (M=16, 8 pad)
#define RSTRIDE 272               // bytes per m-row: 64 cells*4B + 16B pad
#define HBUF_SZ (16 * RSTRIDE)
#define HF_OFF  (2 * HBUF_SZ)     // fp32 h area for final FC
#define ARENA_SZ (HF_OFF + 16 * 64 * 4)

__device__ __forceinline__ float fsig(float x) {
    float e = __builtin_amdgcn_exp2f(-1.442695040888963f * x);
    return __builtin_amdgcn_rcpf(1.0f + e);
}
__device__ __forceinline__ float ftanh(float x) {
    float e = __builtin_amdgcn_exp2f(2.885390081777927f * x);
    return 1.0f - 2.0f * __builtin_amdgcn_rcpf(e + 1.0f);
}
// round-to-nearest bf16 split: low short = hi(f), high short = lo(f - hi)
__device__ __forceinline__ unsigned pack_hilo(float f) {
    unsigned u  = __float_as_uint(f);
    unsigned hi = (u + 0x7fffu + ((u >> 16) & 1u)) >> 16;
    float    fh = __uint_as_float(hi << 16);
    float    rl = f - fh;
    unsigned ul = __float_as_uint(rl);
    unsigned lo = (ul + 0x7fffu + ((ul >> 16) & 1u)) >> 16;
    return (hi & 0xFFFFu) | (lo << 16);
}

__global__ __launch_bounds__(256, 2) void lstm_mfma2_kernel(
    const float* __restrict__ x,     // [B,T,2]
    const float* __restrict__ W_ih,  // [200,2]
    const float* __restrict__ W_hh,  // [200,50]
    const float* __restrict__ b_ih,  // [200]
    const float* __restrict__ b_hh,  // [200]
    const float* __restrict__ W_fc,  // [3,50]
    const float* __restrict__ b_fc,  // [3]
    float* __restrict__ out)         // [B,3]
{
    __shared__ __align__(16) char arena[ARENA_SZ];

    const int tid  = threadIdx.x;
    const int lane = tid & 63;
    const int wv   = tid >> 6;         // u-block 0..3
    const int col  = lane & 15;        // C col (unit) / A row (m) index
    const int grp  = lane >> 4;        // k-group / C row group
    const int u    = wv * 16 + col;    // owned unit (0..63, 50 real)
    const int b0   = blockIdx.x * ROWS;

    // ---- zero arena ----
    for (int i = tid; i < ARENA_SZ / 4; i += 256) ((int*)arena)[i] = 0;

    // ---- B-frags in regs: k carries units + x-slots + bias-slot ----
    bf16x8 whi[4][2], wlo[4][2];
#pragma unroll
    for (int g = 0; g < 4; ++g) {
#pragma unroll
        for (int kt = 0; kt < 2; ++kt) {
            bf16x8 H, L;
#pragma unroll
            for (int e = 0; e < 8; ++e) {
                int k = kt * 32 + grp * 8 + e;
                float v = 0.f;
                if (u < HID) {
                    int j = g * HID + u;
                    if      (k < HID)  v = W_hh[j * HID + k];
                    else if (k == 50)  v = W_ih[2 * j + 0];
                    else if (k == 51)  v = W_ih[2 * j + 1];
                    else if (k == 52)  v = b_ih[j] + b_hh[j];
                }
                unsigned p = pack_hilo(v);
                H[e] = (short)(p & 0xFFFFu);
                L[e] = (short)(p >> 16);
            }
            whi[g][kt] = H;
            wlo[g][kt] = L;
        }
    }

    __syncthreads();   // zeroing complete

    // k=52 const-1.0 cells (hi=0x3F80, lo=0), both buffers
    if (tid < 32) {
        int buf = tid >> 4, m = tid & 15;
        *(unsigned*)(arena + buf * HBUF_SZ + m * RSTRIDE + 52 * 4) = 0x00003F80u;
    }
    // x writer lanes: wave 0, 16 lanes -> (m 0..7) x (component 0..1)
    const int  xm = lane & 15;
    const int  xw = (lane >> 4) & 1;
    const bool xwriter = (wv == 0) && (lane < 32) && (xm < ROWS);
    const float* xptr = x + (size_t)(b0 + xm) * (T_STEPS * 2) + xw;
    if (xwriter)   // x(t=0) into buffer 0
        *(unsigned*)(arena + xm * RSTRIDE + (50 + xw) * 4) = pack_hilo(xptr[0]);
    float xpre = xwriter ? xptr[1 * 2] : 0.f;   // prefetch x(t=1)

    float c4[4]   = {0.f, 0.f, 0.f, 0.f};
    float hreg[4] = {0.f, 0.f, 0.f, 0.f};

    __syncthreads();

    int pb = 0;
    for (int t = 0; t < T_STEPS; ++t) {
        // ---- A-frags: 4x ds_read_b128 + shift/or deinterleave ----
        const char* hb = arena + pb * HBUF_SZ + col * RSTRIDE;
        bf16x8 ah[2], al[2];
#pragma unroll
        for (int kt = 0; kt < 2; ++kt) {
            const char* p = hb + kt * 128 + grp * 32;
            uint4 sA = *(const uint4*)p;
            uint4 sB = *(const uint4*)(p + 16);
            union { unsigned d[4]; bf16x8 v; } H, L;
            H.d[0] = (sA.x & 0xFFFFu) | (sA.y << 16);
            L.d[0] = (sA.x >> 16)     | (sA.y & 0xFFFF0000u);
            H.d[1] = (sA.z & 0xFFFFu) | (sA.w << 16);
            L.d[1] = (sA.z >> 16)     | (sA.w & 0xFFFF0000u);
            H.d[2] = (sB.x & 0xFFFFu) | (sB.y << 16);
            L.d[2] = (sB.x >> 16)     | (sB.y & 0xFFFF0000u);
            H.d[3] = (sB.z & 0xFFFFu) | (sB.w << 16);
            L.d[3] = (sB.z >> 16)     | (sB.w & 0xFFFF0000u);
            ah[kt] = H.v;
            al[kt] = L.v;
        }

        // ---- 4 gate tiles x (2 kt x 3 emulation terms) = 24 MFMA ----
        f32x4 acc[4];
#pragma unroll
        for (int g = 0; g < 4; ++g) {
            f32x4 a = {0.f, 0.f, 0.f, 0.f};
            a = __builtin_amdgcn_mfma_f32_16x16x32_bf16(ah[0], whi[g][0], a, 0, 0, 0);
            a = __builtin_amdgcn_mfma_f32_16x16x32_bf16(ah[1], whi[g][1], a, 0, 0, 0);
            a = __builtin_amdgcn_mfma_f32_16x16x32_bf16(al[0], whi[g][0], a, 0, 0, 0);
            a = __builtin_amdgcn_mfma_f32_16x16x32_bf16(al[1], whi[g][1], a, 0, 0, 0);
            a = __builtin_amdgcn_mfma_f32_16x16x32_bf16(ah[0], wlo[g][0], a, 0, 0, 0);
            a = __builtin_amdgcn_mfma_f32_16x16x32_bf16(ah[1], wlo[g][1], a, 0, 0, 0);
            acc[g] = a;
        }

        // ---- epilogue: acc IS the preactivation; update c, publish h ----
        char* db = arena + (pb ^ 1) * HBUF_SZ;
#pragma unroll
        for (int r = 0; r < 4; ++r) {
            float ig = fsig(acc[0][r]);
            float fg = fsig(acc[1][r]);
            float gg = ftanh(acc[2][r]);
            float og = fsig(acc[3][r]);
            float c  = fg * c4[r] + ig * gg;
            c4[r] = c;
            float h = og * ftanh(c);
            hreg[r] = h;
            if (u < HID) {
                int m = grp * 4 + r;
                *(unsigned*)(db + m * RSTRIDE + u * 4) = pack_hilo(h);
            }
        }

        // ---- x(t+1) into next buffer; prefetch x(t+2) ----
        if (xwriter) {
            *(unsigned*)(db + xm * RSTRIDE + (50 + xw) * 4) = pack_hilo(xpre);
            int t2 = (t + 2 < T_STEPS) ? t + 2 : T_STEPS - 1;
            xpre = xptr[(size_t)t2 * 2];
        }

        pb ^= 1;
        __syncthreads();
    }

    // ---- final FC: gather fp32 h, 24 threads compute out ----
    float* hf = (float*)(arena + HF_OFF);   // [16][64]
#pragma unroll
    for (int r = 0; r < 4; ++r)
        hf[(grp * 4 + r) * 64 + u] = hreg[r];
    __syncthreads();
    if (tid < ROWS * 3) {
        int m = tid / 3, o = tid - m * 3;
        float s = b_fc[o];
        for (int k = 0; k < HID; ++k)
            s += hf[m * 64 + k] * W_fc[o * HID + k];
        out[(size_t)(b0 + m) * 3 + o] = s;
    }
}

extern "C" void kernel_launch(void* const* d_in, const int* in_sizes, int n_in,
                              void* d_out, int out_size, void* d_ws, size_t ws_size,
                              hipStream_t stream) {
    const float* x    = (const float*)d_in[0];
    const float* W_ih = (const float*)d_in[1];
    const float* W_hh = (const float*)d_in[2];
    const float* b_ih = (const float*)d_in[3];
    const float* b_hh = (const float*)d_in[4];
    const float* W_fc = (const float*)d_in[5];
    const float* b_fc = (const float*)d_in[6];
    float* out = (float*)d_out;

    dim3 grid(4096 / ROWS);   // 512 blocks
    dim3 block(256);          // 4 waves
    lstm_mfma2_kernel<<<grid, block, 0, stream>>>(x, W_ih, W_hh, b_ih, b_hh,
                                                  W_fc, b_fc, out);
}

// Round 7
// 369.687 us; speedup vs baseline: 2.2818x; 1.5143x over previous
//
#include <hip/hip_runtime.h>

// LSTM B=4096, T=512, I=2, H=50, O=3 — MFMA bf16x3, round 7.
// Changes vs round 6:
//  * ROWS=16: all 16 C-tile rows are REAL batch rows (no pad-row epilogue
//    waste). 256 blocks x 4 waves -> 1 block/CU, 1 wave/SIMD.
//  * h layout: per m-row, 8 k-chunks of [hi8(16B)][lo8(16B)] -> A-frags are
//    4 raw ds_read_b128 (no deinterleave VALU); h publish = 8 ds_write_b16.
// K-dim still carries everything: k=0..49 h, k=50/51 x0/x1, k=52 const 1.0,
// so acc == full gate preactivation. Double-buffered, ONE barrier per t.

typedef short bf16x8 __attribute__((ext_vector_type(8)));
typedef float f32x4  __attribute__((ext_vector_type(4)));

#define T_STEPS 512
#define HID     50
#define ROWS    16
#define RSTRIDE 272                        // 17 x 16B granules per m-row
#define HBUF_SZ (ROWS * RSTRIDE)           // 4352 B
#define HF_OFF  (2 * HBUF_SZ)              // 8704 B
#define ARENA_SZ (HF_OFF + ROWS * 64 * 4)  // 12800 B

__device__ __forceinline__ float fsig(float x) {
    float e = __builtin_amdgcn_exp2f(-1.442695040888963f * x);
    return __builtin_amdgcn_rcpf(1.0f + e);
}
__device__ __forceinline__ float ftanh(float x) {
    float e = __builtin_amdgcn_exp2f(2.885390081777927f * x);
    return 1.0f - 2.0f * __builtin_amdgcn_rcpf(e + 1.0f);
}
// (hi bf16 in low short, lo bf16 in high short), round-to-nearest both
__device__ __forceinline__ unsigned pack_hilo(float f) {
    unsigned u  = __float_as_uint(f);
    unsigned hi = (u + 0x7fffu + ((u >> 16) & 1u)) >> 16;
    float    fh = __uint_as_float(hi << 16);
    float    rl = f - fh;
    unsigned ul = __float_as_uint(rl);
    unsigned lo = (ul + 0x7fffu + ((ul >> 16) & 1u)) >> 16;
    return (hi & 0xFFFFu) | (lo << 16);
}

__global__ __launch_bounds__(256, 1) void lstm_mfma3_kernel(
    const float* __restrict__ x,     // [B,T,2]
    const float* __restrict__ W_ih,  // [200,2]
    const float* __restrict__ W_hh,  // [200,50]
    const float* __restrict__ b_ih,  // [200]
    const float* __restrict__ b_hh,  // [200]
    const float* __restrict__ W_fc,  // [3,50]
    const float* __restrict__ b_fc,  // [3]
    float* __restrict__ out)         // [B,3]
{
    __shared__ __align__(16) char arena[ARENA_SZ];

    const int tid  = threadIdx.x;
    const int lane = tid & 63;
    const int wv   = tid >> 6;         // u-block 0..3
    const int col  = lane & 15;        // C col (unit) / A row (m) index
    const int grp  = lane >> 4;        // k-group / C row-group
    const int u    = wv * 16 + col;    // owned unit (0..63, 50 real)
    const int b0   = blockIdx.x * ROWS;

    // ---- zero arena ----
    for (int i = tid; i < ARENA_SZ / 4; i += 256) ((int*)arena)[i] = 0;

    // ---- B-frags in regs: k carries units + x-slots + bias-slot ----
    bf16x8 whi[4][2], wlo[4][2];
#pragma unroll
    for (int g = 0; g < 4; ++g) {
#pragma unroll
        for (int kt = 0; kt < 2; ++kt) {
            bf16x8 H, L;
#pragma unroll
            for (int e = 0; e < 8; ++e) {
                int k = kt * 32 + grp * 8 + e;
                float v = 0.f;
                if (u < HID) {
                    int j = g * HID + u;
                    if      (k < HID)  v = W_hh[j * HID + k];
                    else if (k == 50)  v = W_ih[2 * j + 0];
                    else if (k == 51)  v = W_ih[2 * j + 1];
                    else if (k == 52)  v = b_ih[j] + b_hh[j];
                }
                unsigned p = pack_hilo(v);
                H[e] = (short)(p & 0xFFFFu);
                L[e] = (short)(p >> 16);
            }
            whi[g][kt] = H;
            wlo[g][kt] = L;
        }
    }

    __syncthreads();   // zeroing complete

    // const-1.0 at k=52 (chunk 6, elems 4..5 as one b32: hi(k52)=0x3F80,
    // hi(k53)=0), both buffers; lo plane stays zero.
    if (tid < 2 * ROWS) {
        int buf = tid >> 4, m = tid & 15;
        *(unsigned*)(arena + buf * HBUF_SZ + m * RSTRIDE + 6 * 32 + 4 * 2) = 0x00003F80u;
    }
    // x writer lanes: wave 0, lanes 0..31 -> (m 0..15) x (component 0..1)
    const int  xm = lane & 15;
    const int  xw = (lane >> 4) & 1;
    const bool xwriter = (wv == 0) && (lane < 32);
    const float* xptr = x + (size_t)(b0 + xm) * (T_STEPS * 2) + xw;
    if (xwriter) {   // x(t=0) into buffer 0: k=50+xw -> chunk 6, elem 2+xw
        unsigned p = pack_hilo(xptr[0]);
        char* cell = arena + xm * RSTRIDE + 6 * 32 + (2 + xw) * 2;
        *(short*)cell        = (short)(p & 0xFFFFu);
        *(short*)(cell + 16) = (short)(p >> 16);
    }
    float xpre = xwriter ? xptr[1 * 2] : 0.f;   // prefetch x(t=1)

    float c4[4]   = {0.f, 0.f, 0.f, 0.f};
    float hreg[4] = {0.f, 0.f, 0.f, 0.f};

    __syncthreads();

    int pb = 0;
    for (int t = 0; t < T_STEPS; ++t) {
        // ---- A-frags: 4 raw ds_read_b128, no deinterleave ----
        const char* hb = arena + pb * HBUF_SZ + col * RSTRIDE;
        bf16x8 ah[2], al[2];
#pragma unroll
        for (int kt = 0; kt < 2; ++kt) {
            const char* p = hb + (kt * 4 + grp) * 32;
            ah[kt] = *(const bf16x8*)p;
            al[kt] = *(const bf16x8*)(p + 16);
        }

        // ---- 4 gate tiles x (2 kt x 3 emulation terms) = 24 MFMA ----
        f32x4 acc[4];
#pragma unroll
        for (int g = 0; g < 4; ++g) {
            f32x4 a = {0.f, 0.f, 0.f, 0.f};
            a = __builtin_amdgcn_mfma_f32_16x16x32_bf16(ah[0], whi[g][0], a, 0, 0, 0);
            a = __builtin_amdgcn_mfma_f32_16x16x32_bf16(ah[1], whi[g][1], a, 0, 0, 0);
            a = __builtin_amdgcn_mfma_f32_16x16x32_bf16(al[0], whi[g][0], a, 0, 0, 0);
            a = __builtin_amdgcn_mfma_f32_16x16x32_bf16(al[1], whi[g][1], a, 0, 0, 0);
            a = __builtin_amdgcn_mfma_f32_16x16x32_bf16(ah[0], wlo[g][0], a, 0, 0, 0);
            a = __builtin_amdgcn_mfma_f32_16x16x32_bf16(ah[1], wlo[g][1], a, 0, 0, 0);
            acc[g] = a;
        }

        // ---- epilogue: acc IS the preactivation; update c, publish h ----
        char* db = arena + (pb ^ 1) * HBUF_SZ;
#pragma unroll
        for (int r = 0; r < 4; ++r) {
            float ig = fsig(acc[0][r]);
            float fg = fsig(acc[1][r]);
            float gg = ftanh(acc[2][r]);
            float og = fsig(acc[3][r]);
            float c  = fg * c4[r] + ig * gg;
            c4[r] = c;
            float h = og * ftanh(c);
            hreg[r] = h;
            if (u < HID) {
                int m = grp * 4 + r;                 // 0..15, all real
                unsigned p = pack_hilo(h);
                char* cell = db + m * RSTRIDE + (u >> 3) * 32 + (u & 7) * 2;
                *(short*)cell        = (short)(p & 0xFFFFu);
                *(short*)(cell + 16) = (short)(p >> 16);
            }
        }

        // ---- x(t+1) into next buffer; prefetch x(t+2) ----
        if (xwriter) {
            unsigned p = pack_hilo(xpre);
            char* cell = db + xm * RSTRIDE + 6 * 32 + (2 + xw) * 2;
            *(short*)cell        = (short)(p & 0xFFFFu);
            *(short*)(cell + 16) = (short)(p >> 16);
            int t2 = (t + 2 < T_STEPS) ? t + 2 : T_STEPS - 1;
            xpre = xptr[(size_t)t2 * 2];
        }

        pb ^= 1;
        __syncthreads();
    }

    // ---- final FC: gather fp32 h, 48 threads compute out ----
    float* hf = (float*)(arena + HF_OFF);   // [16][64]
#pragma unroll
    for (int r = 0; r < 4; ++r)
        hf[(grp * 4 + r) * 64 + u] = hreg[r];
    __syncthreads();
    if (tid < ROWS * 3) {
        int m = tid / 3, o = tid - m * 3;
        float s = b_fc[o];
        for (int k = 0; k < HID; ++k)
            s += hf[m * 64 + k] * W_fc[o * HID + k];
        out[(size_t)(b0 + m) * 3 + o] = s;
    }
}

extern "C" void kernel_launch(void* const* d_in, const int* in_sizes, int n_in,
                              void* d_out, int out_size, void* d_ws, size_t ws_size,
                              hipStream_t stream) {
    const float* x    = (const float*)d_in[0];
    const float* W_ih = (const float*)d_in[1];
    const float* W_hh = (const float*)d_in[2];
    const float* b_ih = (const float*)d_in[3];
    const float* b_hh = (const float*)d_in[4];
    const float* W_fc = (const float*)d_in[5];
    const float* b_fc = (const float*)d_in[6];
    float* out = (float*)d_out;

    dim3 grid(4096 / ROWS);   // 256 blocks -> 1 per CU
    dim3 block(256);          // 4 waves
    lstm_mfma3_kernel<<<grid, block, 0, stream>>>(x, W_ih, W_hh, b_ih, b_hh,
                                                  W_fc, b_fc, out);
}